// Round 9
// baseline (1257.891 us; speedup 1.0000x reference)
//
#include <hip/hip_runtime.h>
#include <hip/hip_bf16.h>

#define BB 2
#define NN 4096
#define CH 64
#define KW 8              // slice waves per KNN block
#define SLICE (NN / KW)   // 512 rows per slice

typedef __bf16 bf16x8 __attribute__((ext_vector_type(8)));
typedef float f32x4 __attribute__((ext_vector_type(4)));
typedef unsigned long long u64;

__device__ __forceinline__ float lrelu(float v) { return fmaxf(v, 0.1f * v); }
__device__ __forceinline__ float tobf(const __hip_bfloat16& h) { return __bfloat162float(h); }

// canonical f32 input region offsets (element offsets within cn)
#define PC1_C 0
#define PC2_C 24576
#define F1_C 49152
#define F2_C 573440
#define K1_C 1097728
#define K2_C 1622016
#define WT11_C 2146304
#define BT11_C 2150400
#define WT22_C 2150464
#define BT22_C 2154560
#define WPOS_C 2154624
#define BPOS_C 2154816
#define WM1_C 2154880
#define BM1_C 2158976
#define WM2_C 2159040
#define BM2_C 2163136
#define CN_TOTAL 2163200

// monotone u32 key for f32 (handles negatives): ascending uint == ascending float
__device__ __forceinline__ unsigned fmono(float f) {
  unsigned u = __float_as_uint(f);
  return u ^ ((unsigned)((int)u >> 31) | 0x80000000u);
}

// branchless sorted-ascending top-8 on u64 keys (key = dist_mono<<32 | id).
// Exact total order -> no tie ambiguity; lower id wins equal-dist by construction.
__device__ __forceinline__ void ins8(u64 k[8], u64 nk) {
#pragma unroll
  for (int p = 0; p < 8; ++p) {
    u64 mn = nk < k[p] ? nk : k[p];
    nk = nk < k[p] ? k[p] : nk;
    k[p] = mn;
  }
}

// quad-wide sum via DPP quad_perm (VALU pipe, no LDS): returns (p0+p1)+(p2+p3)
// bit-identically on all 4 quad lanes (f32 add is bitwise commutative).
__device__ __forceinline__ float qsum(float p) {
  int i = __float_as_int(p);
  int t = __builtin_amdgcn_update_dpp(i, i, 0xB1, 0xF, 0xF, true);  // quad_perm [1,0,3,2]
  float s = p + __int_as_float(t);
  int i2 = __float_as_int(s);
  int t2 = __builtin_amdgcn_update_dpp(i2, i2, 0x4E, 0xF, 0xF, true);  // quad_perm [2,3,0,1]
  return s + __int_as_float(t2);
}

// one 16-channel quarter dot; SHARED by scan and recovery -> bit-identical values
__device__ __forceinline__ float dot_quarter(const float* __restrict__ drow,
                                             const float* __restrict__ qrow) {
  const f32x4* a = reinterpret_cast<const f32x4*>(drow);
  const f32x4* b = reinterpret_cast<const f32x4*>(qrow);
  f32x4 c = a[0] * b[0];
  c = a[1] * b[1] + c;
  c = a[2] * b[2] + c;
  c = a[3] * b[3] + c;
  return (c[0] + c[1]) + (c[2] + c[3]);
}

__device__ __forceinline__ float cosdist(const float* __restrict__ drow,
                                         const float* __restrict__ qrow) {
  float p0 = dot_quarter(drow, qrow);
  float p1 = dot_quarter(drow + 16, qrow + 16);
  float p2 = dot_quarter(drow + 32, qrow + 32);
  float p3 = dot_quarter(drow + 48, qrow + 48);
  return 1.0f - ((p0 + p1) + (p2 + p3));
}

__device__ __forceinline__ float eucdist(float4 a, float4 p) {
  return a.w + p.w - 2.f * (a.x * p.x + a.y * p.y + a.z * p.z);
}

// ---- dtype detector (proven R3/R4): f32-as-bf16 shows ~45% exponents >= 140
__global__ void k_detect(const unsigned short* __restrict__ pc1raw, int* __restrict__ flag) {
  int lane = threadIdx.x;  // 64
  int bad = 0;
#pragma unroll
  for (int i = 0; i < 64; ++i) {
    unsigned short u = pc1raw[lane * 64 + i];
    int e = (u >> 7) & 0xFF;
    bad += (e >= 140) ? 1 : 0;
  }
#pragma unroll
  for (int s = 32; s; s >>= 1) bad += __shfl_xor(bad, s, 64);
  if (lane == 0) *flag = (bad > 16) ? 1 : 0;  // 1 = inputs are float32
}

// ---- ingest: all 16 inputs -> canonical f32 + sanitize
__global__ __launch_bounds__(256) void k_ingest(
    const void* p0, const void* p1, const void* p2, const void* p3,
    const void* p4, const void* p5, const void* p6, const void* p7,
    const void* p8, const void* p9, const void* p10, const void* p11,
    const void* p12, const void* p13, const void* p14, const void* p15,
    const int* __restrict__ flag, float* __restrict__ dst) {
  const int cum[17] = {0, 24576, 49152, 573440, 1097728, 1622016, 2146304, 2150400,
                       2150464, 2154560, 2154624, 2154816, 2154880, 2158976, 2159040,
                       2163136, 2163200};
  size_t t = (size_t)blockIdx.x * 256 + threadIdx.x;
  if (t >= (size_t)CN_TOTAL) return;
  int seg = 0;
#pragma unroll
  for (int i = 1; i < 16; ++i) seg += (t >= (size_t)cum[i]) ? 1 : 0;
  size_t local = t - (size_t)cum[seg];
  const void* ptrs[16] = {p0, p1, p2, p3, p4, p5, p6, p7, p8, p9, p10, p11, p12, p13, p14, p15};
  const void* p = ptrs[seg];
  float v;
  if (*flag) v = ((const float*)p)[local];
  else       v = tobf(((const __hip_bfloat16*)p)[local]);
  if (!(v == v) || fabsf(v) > 1e30f) v = 0.f;
  dst[t] = v;
}

// ---- Wm1/Wm2 -> bf16 canonical
__global__ void k_prep_wm(const float* __restrict__ cn, __hip_bfloat16* __restrict__ wmb) {
  int t = blockIdx.x * 256 + threadIdx.x;  // 8192
  float v = (t < 4096) ? cn[WM1_C + t] : cn[WM2_C + (t - 4096)];
  wmb[t] = __float2bfloat16(v);
}

// ---- prep: pc -> float4(x,y,z,|p|^2)
__global__ __launch_bounds__(256) void k_prep_xyz(const float* __restrict__ cn,
                                                  float4* __restrict__ xyzt) {
  int t = blockIdx.x * 256 + threadIdx.x;
  int n = t & (NN - 1);
  int b = (t >> 12) & 1;
  int a = t >> 13;
  const float* p = cn + (a ? PC2_C : PC1_C) + (size_t)b * 3 * NN + n;
  float x = p[0], y = p[NN], z = p[2 * NN];
  xyzt[(size_t)(a * BB + b) * NN + n] = make_float4(x, y, z, x * x + y * y + z * z);
}

// ---- prep: W_pos + b_pos -> float4
__global__ void k_prep_wpos(const float* __restrict__ cn, float4* __restrict__ wp4) {
  int c = threadIdx.x;  // 64
  wp4[c] = make_float4(cn[WPOS_C + 3 * c], cn[WPOS_C + 3 * c + 1], cn[WPOS_C + 3 * c + 2],
                       cn[BPOS_C + c]);
}

// ---- prep: knn -> row-normalized f32 [2][B][N][64]
__global__ __launch_bounds__(256) void k_prep_knn(const float* __restrict__ cn,
                                                  float* __restrict__ knnt) {
  int t = blockIdx.x * 256 + threadIdx.x;
  int n = t & (NN - 1);
  int b = (t >> 12) & 1;
  int a = t >> 13;
  const float* col = cn + (a ? K2_C : K1_C) + (size_t)b * CH * NN + n;
  float s = 0.f;
#pragma unroll
  for (int c = 0; c < CH; ++c) { float v = col[(size_t)c * NN]; s += v * v; }
  float inv = 1.0f / sqrtf(s + 1e-8f);
  float* o = knnt + ((size_t)(a * BB + b) * NN + n) * CH;
#pragma unroll
  for (int c = 0; c < CH; ++c) o[c] = col[(size_t)c * NN] * inv;
}

// ---- 1x1 convs
__global__ __launch_bounds__(256) void k_conv(const float* __restrict__ cn,
                                              float* __restrict__ fbuf) {
  __shared__ float wl[CH * CH];
  int bid = blockIdx.x;
  int tile = bid & (NN / 4 - 1);
  int b = (bid >> 10) & 1;
  int sel = bid >> 11;
  const float* W = cn + ((sel == 0 || sel == 2) ? WT11_C : WT22_C);
  const float* bias = cn + ((sel == 0 || sel == 2) ? BT11_C : BT22_C);
  const float* feat = cn + ((sel == 0 || sel == 3) ? F1_C : F2_C);
  int t = threadIdx.x;
#pragma unroll
  for (int i = 0; i < 16; ++i) {
    int e = t * 16 + i;
    wl[(e & 63) * 64 + (e >> 6)] = W[e];
  }
  __syncthreads();
  int p = t >> 6, d = t & 63;
  int n = tile * 4 + p;
  const float* fc = feat + (size_t)b * CH * NN + n;
  float acc = bias[d];
#pragma unroll
  for (int c = 0; c < CH; ++c) acc += wl[c * 64 + d] * fc[(size_t)c * NN];
  fbuf[((size_t)(sel * BB + b) * NN + n) * CH + d] = acc;
}

// ---- R9 fused KNN: group-of-8-row min selection + exact recovery.
// Quad layout: lq=lane>>2 (16 queries/block), qq=lane&3 (16-ch quarter, 4 regs).
// Scan: per row 1 fminf; DPP quad-combine (no LDS pipe); one u64 insert per 8
// rows. Selected top-8 groups per query are PROVEN to contain the true top-8
// elements (contiguous ascending row groups + (gmin,gid) key order). Recovery
// rescoring uses the same inlined fp expressions -> bit-identical distances.
__global__ __launch_bounds__(512, 4) void k_knn(const float* __restrict__ knnt,
                                                const float4* __restrict__ xyzt,
                                                int* __restrict__ idxf) {
  __shared__ u64 ck[KW * 16 * 8];  // 8 KB: slice candidate lists; reused as rk[16][64]
  __shared__ u64 ck2[32 * 8];      // 2 KB: stage-A lists
  __shared__ int fgi[16 * 8];      // final group ids per query
  const int bid = blockIdx.x;  // 1024: x(1)|b(1)|qt(8)
  const int qt = bid & 255;
  const int b = (bid >> 8) & 1;
  const int x = bid >> 9;
  const int tid = threadIdx.x;
  const int w = tid >> 6, lane = tid & 63;
  const int lq = lane >> 2, qq = lane & 3;
  const int q = qt * 16 + lq;
  const int j0 = w * SLICE;
  const float* qbase = knnt + (size_t)(x * BB + b) * NN * CH;
  const float* db = knnt + (size_t)((1 - x) * BB + b) * NN * CH;
  const float4* qxz = xyzt + (size_t)(x * BB + b) * NN;
  const float4* dxz = xyzt + (size_t)((1 - x) * BB + b) * NN;

  u64 ks[8];

  // ========== phase 1: cosine ==========
  {
    const float* qrow = qbase + (size_t)q * CH + qq * 16;
#pragma unroll
    for (int k = 0; k < 8; ++k) ks[k] = ~0ull;
    for (int g = 0; g < 64; ++g) {
      float gmin = 1e30f;
#pragma unroll
      for (int rr = 0; rr < 8; ++rr) {
        const float* rp = db + (size_t)(j0 + g * 8 + rr) * CH + qq * 16;
        float d = 1.0f - qsum(dot_quarter(rp, qrow));
        gmin = fminf(gmin, d);
      }
      ins8(ks, ((u64)fmono(gmin) << 32) | (unsigned)(w * 64 + g));
    }
    if (qq == 0)
#pragma unroll
      for (int k = 0; k < 8; ++k) ck[(w * 16 + lq) * 8 + k] = ks[k];
  }
  __syncthreads();
  if (tid < 32) {  // stage A: merge 4 slice-lists
    int lqA = tid >> 1, h = tid & 1;
    u64 m[8];
#pragma unroll
    for (int k = 0; k < 8; ++k) m[k] = ~0ull;
    for (int i = 0; i < 4; ++i)
      for (int k = 0; k < 8; ++k) ins8(m, ck[((h * 4 + i) * 16 + lqA) * 8 + k]);
#pragma unroll
    for (int k = 0; k < 8; ++k) ck2[tid * 8 + k] = m[k];
  }
  __syncthreads();
  if (tid < 16) {  // stage B: final top-8 groups per query
    u64 m[8];
#pragma unroll
    for (int k = 0; k < 8; ++k) m[k] = ~0ull;
    for (int i = 0; i < 2; ++i)
      for (int k = 0; k < 8; ++k) ins8(m, ck2[(tid * 2 + i) * 8 + k]);
#pragma unroll
    for (int k = 0; k < 8; ++k) fgi[tid * 8 + k] = (int)(unsigned)(m[k] & 0xFFFFFFFFull);
  }
  __syncthreads();
  {  // recovery: 8 groups x 8 rows exact rescore; wave wv -> queries 2wv, 2wv+1
    int qy = (tid >> 6) * 2 + ((lane >> 5) & 1);
    int s = lane & 31;
    const float* qr = qbase + (size_t)(qt * 16 + qy) * CH;
#pragma unroll
    for (int rr = 0; rr < 2; ++rr) {
      int idx = rr * 32 + s;
      int row = fgi[qy * 8 + (idx >> 3)] * 8 + (idx & 7);
      float d = cosdist(db + (size_t)row * CH, qr);
      ck[qy * 64 + idx] = ((u64)fmono(d) << 32) | (unsigned)row;
    }
  }
  __syncthreads();
  if (tid < 16) {  // final element top-8 (key = dist_mono | row: j-tie-break exact)
    u64 m[8];
#pragma unroll
    for (int k = 0; k < 8; ++k) m[k] = ~0ull;
    for (int c = 0; c < 64; ++c) ins8(m, ck[tid * 64 + c]);
    int* o = idxf + (((size_t)x * BB + b) * NN + qt * 16 + tid) * 16;
#pragma unroll
    for (int k = 0; k < 8; ++k) o[k] = (int)(unsigned)(m[k] & 0xFFFFFFFFull);
  }
  __syncthreads();

  // ========== phase 2: euclid ==========
  {
    float4 q4 = qxz[q];
#pragma unroll
    for (int k = 0; k < 8; ++k) ks[k] = ~0ull;
    for (int g = 0; g < 64; ++g) {
      float gmin = 1e30f;
#pragma unroll
      for (int rr = 0; rr < 8; ++rr) {
        float4 p = dxz[j0 + g * 8 + rr];  // wave-uniform address
        gmin = fminf(gmin, eucdist(q4, p));
      }
      ins8(ks, ((u64)fmono(gmin) << 32) | (unsigned)(w * 64 + g));
    }
    if (qq == 0)
#pragma unroll
      for (int k = 0; k < 8; ++k) ck[(w * 16 + lq) * 8 + k] = ks[k];
  }
  __syncthreads();
  if (tid < 32) {
    int lqA = tid >> 1, h = tid & 1;
    u64 m[8];
#pragma unroll
    for (int k = 0; k < 8; ++k) m[k] = ~0ull;
    for (int i = 0; i < 4; ++i)
      for (int k = 0; k < 8; ++k) ins8(m, ck[((h * 4 + i) * 16 + lqA) * 8 + k]);
#pragma unroll
    for (int k = 0; k < 8; ++k) ck2[tid * 8 + k] = m[k];
  }
  __syncthreads();
  if (tid < 16) {
    u64 m[8];
#pragma unroll
    for (int k = 0; k < 8; ++k) m[k] = ~0ull;
    for (int i = 0; i < 2; ++i)
      for (int k = 0; k < 8; ++k) ins8(m, ck2[(tid * 2 + i) * 8 + k]);
#pragma unroll
    for (int k = 0; k < 8; ++k) fgi[tid * 8 + k] = (int)(unsigned)(m[k] & 0xFFFFFFFFull);
  }
  __syncthreads();
  {
    int qy = (tid >> 6) * 2 + ((lane >> 5) & 1);
    int s = lane & 31;
    float4 q4r = qxz[qt * 16 + qy];
#pragma unroll
    for (int rr = 0; rr < 2; ++rr) {
      int idx = rr * 32 + s;
      int row = fgi[qy * 8 + (idx >> 3)] * 8 + (idx & 7);
      float d = eucdist(q4r, dxz[row]);
      ck[qy * 64 + idx] = ((u64)fmono(d) << 32) | (unsigned)row;
    }
  }
  __syncthreads();
  if (tid < 16) {
    u64 m[8];
#pragma unroll
    for (int k = 0; k < 8; ++k) m[k] = ~0ull;
    for (int c = 0; c < 64; ++c) ins8(m, ck[tid * 64 + c]);
    int* o = idxf + (((size_t)x * BB + b) * NN + qt * 16 + tid) * 16 + 8;
#pragma unroll
    for (int k = 0; k < 8; ++k) o[k] = (int)(unsigned)(m[k] & 0xFFFFFFFFull);
  }
}

// ---- fused gather + pos-conv + 2x MFMA MLP + neighbor max (proven R4-R8).
__global__ __launch_bounds__(256) void k_mlp(const float* __restrict__ fbuf,
                                             const float4* __restrict__ xyzt,
                                             const int* __restrict__ idxf,
                                             const float4* __restrict__ wp4,
                                             const __hip_bfloat16* __restrict__ wmb,
                                             const float* __restrict__ cn,
                                             float* __restrict__ out) {
  __shared__ __bf16 h1s[4 * 16 * 72];
  const int t = threadIdx.x;
  const int wv = t >> 6, L = t & 63;
  const int lo = L & 15, g = L >> 4;
  int bid = blockIdx.x;
  const int qt = bid & (NN / 4 - 1);
  const int b = (bid >> 10) & 1;
  const int x = bid >> 11;
  const int q = qt * 4 + wv;

  bf16x8 w1f[4][2], w2f[4][2];
#pragma unroll
  for (int tt = 0; tt < 4; ++tt)
#pragma unroll
    for (int kc = 0; kc < 2; ++kc) {
      int e = tt * 16 + lo, c0 = kc * 32 + g * 8;
      w1f[tt][kc] = *reinterpret_cast<const bf16x8*>(wmb + e * 64 + c0);
      w2f[tt][kc] = *reinterpret_cast<const bf16x8*>(wmb + 4096 + e * 64 + c0);
    }

  const float* pq  = fbuf + ((size_t)((x ? 2 : 0) * BB + b)) * NN * CH;
  const float* pdb = fbuf + ((size_t)((x ? 3 : 1) * BB + b)) * NN * CH;
  const float4* qx  = xyzt + (size_t)(x * BB + b) * NN;
  const float4* dbx = xyzt + (size_t)((1 - x) * BB + b) * NN;

  const int m = lo;
  int jm = idxf[(((size_t)x * BB + b) * NN + q) * 16 + m];
  jm &= (NN - 1);
  const float4 q4 = qx[q];
  const float4 p4 = dbx[jm];
  const float dx = p4.x - q4.x, dy = p4.y - q4.y, dz = p4.z - q4.z;
  const float* g2p = pdb + (size_t)jm * CH;
  const float* pqp = pq + (size_t)q * CH;

  bf16x8 a0, a1;
#pragma unroll
  for (int kc = 0; kc < 2; ++kc) {
#pragma unroll
    for (int j = 0; j < 8; ++j) {
      int c = kc * 32 + g * 8 + j;
      float4 wp = wp4[c];
      float v = g2p[c] + pqp[c] + wp.x * dx + wp.y * dy + wp.z * dz + wp.w;
      v = lrelu(v);
      if (kc == 0) a0[j] = (__bf16)v; else a1[j] = (__bf16)v;
    }
  }

  __bf16* hrow = h1s + wv * 16 * 72;
#pragma unroll
  for (int tt = 0; tt < 4; ++tt) {
    float bv = cn[BM1_C + tt * 16 + lo];
    f32x4 acc = {bv, bv, bv, bv};
    acc = __builtin_amdgcn_mfma_f32_16x16x32_bf16(a0, w1f[tt][0], acc, 0, 0, 0);
    acc = __builtin_amdgcn_mfma_f32_16x16x32_bf16(a1, w1f[tt][1], acc, 0, 0, 0);
#pragma unroll
    for (int r = 0; r < 4; ++r) {
      float v = lrelu(acc[r]);
      hrow[(g * 4 + r) * 72 + tt * 16 + lo] = (__bf16)v;
    }
  }
  __syncthreads();
  bf16x8 h1a = *reinterpret_cast<const bf16x8*>(hrow + m * 72 + g * 8);
  bf16x8 h1b = *reinterpret_cast<const bf16x8*>(hrow + m * 72 + 32 + g * 8);

  size_t obase = ((size_t)(x * BB + b) * CH) * NN;
#pragma unroll
  for (int tt = 0; tt < 4; ++tt) {
    float bv = cn[BM2_C + tt * 16 + lo];
    f32x4 acc = {bv, bv, bv, bv};
    acc = __builtin_amdgcn_mfma_f32_16x16x32_bf16(h1a, w2f[tt][0], acc, 0, 0, 0);
    acc = __builtin_amdgcn_mfma_f32_16x16x32_bf16(h1b, w2f[tt][1], acc, 0, 0, 0);
    float v = fmaxf(fmaxf(lrelu(acc[0]), lrelu(acc[1])), fmaxf(lrelu(acc[2]), lrelu(acc[3])));
    v = fmaxf(v, __shfl_xor(v, 16, 64));
    v = fmaxf(v, __shfl_xor(v, 32, 64));
    if (g == 0) out[obase + (size_t)(tt * 16 + lo) * NN + q] = v;
  }
}

// workspace layout (float units)
#define CN_OFF 0
#define FB_OFF ((size_t)CN_TOTAL)
#define KT_OFF (FB_OFF + (size_t)4 * BB * NN * CH)
#define XZ_OFF (KT_OFF + (size_t)2 * BB * NN * CH)
#define WP4_OFF (XZ_OFF + (size_t)2 * BB * NN * 4)
#define WMB_OFF (WP4_OFF + 256)
#define IDX_OFF (WMB_OFF + 4096)
#define FLAG_OFF (IDX_OFF + 262144)

extern "C" void kernel_launch(void* const* d_in, const int* in_sizes, int n_in,
                              void* d_out, int out_size, void* d_ws, size_t ws_size,
                              hipStream_t stream) {
  float* ws = (float*)d_ws;
  float* cn = ws + CN_OFF;
  int* flag = (int*)(ws + FLAG_OFF);

  k_detect<<<1, 64, 0, stream>>>((const unsigned short*)d_in[0], flag);
  k_ingest<<<(CN_TOTAL + 255) / 256, 256, 0, stream>>>(
      d_in[0], d_in[1], d_in[2], d_in[3], d_in[4], d_in[5], d_in[6], d_in[7],
      d_in[8], d_in[9], d_in[10], d_in[11], d_in[12], d_in[13], d_in[14], d_in[15],
      flag, cn);
  k_prep_wm<<<32, 256, 0, stream>>>(cn, (__hip_bfloat16*)(ws + WMB_OFF));
  k_prep_xyz<<<(2 * BB * NN) / 256, 256, 0, stream>>>(cn, (float4*)(ws + XZ_OFF));
  k_prep_wpos<<<1, 64, 0, stream>>>(cn, (float4*)(ws + WP4_OFF));
  k_prep_knn<<<(2 * BB * NN) / 256, 256, 0, stream>>>(cn, ws + KT_OFF);
  k_conv<<<4 * BB * (NN / 4), 256, 0, stream>>>(cn, ws + FB_OFF);
  k_knn<<<2 * BB * (NN / 16), 512, 0, stream>>>(ws + KT_OFF, (const float4*)(ws + XZ_OFF),
                                                (int*)(ws + IDX_OFF));
  k_mlp<<<2 * BB * (NN / 4), 256, 0, stream>>>(ws + FB_OFF, (const float4*)(ws + XZ_OFF),
                                               (const int*)(ws + IDX_OFF), (const float4*)(ws + WP4_OFF),
                                               (const __hip_bfloat16*)(ws + WMB_OFF), cn,
                                               (float*)d_out);
}